// Round 8
// baseline (775.724 us; speedup 1.0000x reference)
//
#include <hip/hip_runtime.h>
#include <hip/hip_bf16.h>

// MoE forward, MI355X. B=4,S=2048,H=1024,E=8,F=4096,K=2.
// router (no atomics) -> slots (scan + exact offsets + 256-row tile table) ->
// gather x->bf16 -> grouped MFMA GEMM1 (+gelu) -> grouped GEMM2 (+b2) ->
// combine (p0*(y1+y2)).
// NO weight transposes (R8): W1 [H][F] and W2 [F][H] are already [K][N] fp32.
// B-operand is reg-staged in the K-loop: 16 wave-coalesced fp32 dword loads
// per thread (lane->n), cvt->bf16, 2x ds_write_b128 into the same swizzled
// LDS layout the frag reads use. A-operand staged via global_load_lds from
// bf16 Xg/hb (K-contig) as before. Saves prep's ~470MB transpose traffic.
// GEMM core: BM=256(A) x BN=128(B), BK=32, 256 thr = 4 waves (2Mx2N), each
// wave 128x64 (8x4 frags of 16x16x32). 3-buffer LDS ring (3x24KB=72KB =>
// 2 blocks/CU). vmcnt ledger: B-loads issued BEFORE A-GLD16s each step;
// compiler's exact wait for fb = vmcnt(4), which (in-order retirement) also
// retires A(t+1) -> replaces the old explicit vmcnt(6). sched_barrier(0)
// pins issue order. Raw s_barrier; setprio(1) around MFMA clusters.
// LDS pack: 2 global rows per 128B LDS row, XOR swizzle W^=(p&7)<<4 (A side
// pre-applies inverse XOR on global source; B side applies XOR on ds_write).
// Tile->block map: bijective chunked XCD split (n fastest) for L2 panel reuse.
// Expert segments UNPADDED; tiles may overhang -> mask stores at gm < rowEnd.
// Workspace (bytes), total ~305 MB (W1t/W2t regions now unused):
//   [0,4096)   meta ints: off[0..8], ntiles@[10], tileInfo[<=72]@[16..]
//   [4096,..)  e01[8192] | [36864,..) p0[8192]
//   [69632,..) slot1 | [102400,..) slot2
//   [135168,..)    Xg bf16 [16640][1024] (reused as ybuf)
//   [168431616,..) h  bf16 [16640][4096]  (ends 304746496)

typedef __bf16 bf16;
typedef __attribute__((ext_vector_type(4))) __bf16 bf16x4;
typedef __attribute__((ext_vector_type(8))) __bf16 bf16x8;
typedef __attribute__((ext_vector_type(4))) float f32x4;

#define GLD16(g, l) __builtin_amdgcn_global_load_lds( \
    (__attribute__((address_space(1))) void*)(g),      \
    (__attribute__((address_space(3))) void*)(l), 16, 0, 0)

// gelu tanh-approx == v * sigmoid(2c), 2c = 1.5957691216*v + 0.07135481627*v^3.
__device__ __forceinline__ float gelu_fast(float v) {
  float u = v * fmaf(v * v, 0.0713548162726f, 1.5957691216057308f);
  return v * __builtin_amdgcn_rcpf(1.0f + __expf(-u));
}

// ---------------- router: 1 wave per token, no atomics ----------------
__global__ __launch_bounds__(256) void router_kernel(
    const float* __restrict__ x, const float* __restrict__ Wr,
    const float* __restrict__ br, int* __restrict__ e01,
    float* __restrict__ p0arr) {
  int wv = threadIdx.x >> 6;
  int l = threadIdx.x & 63;
  int t = blockIdx.x * 4 + wv;
  float acc[8];
#pragma unroll
  for (int e = 0; e < 8; e++) acc[e] = 0.f;
  const float* xr = x + (size_t)t * 1024;
#pragma unroll
  for (int i = 0; i < 16; i++) {
    int h = l + i * 64;
    float xv = xr[h];
    const float4* w4 = (const float4*)(Wr + h * 8);
    float4 wa = w4[0], wb = w4[1];
    acc[0] += xv * wa.x; acc[1] += xv * wa.y; acc[2] += xv * wa.z; acc[3] += xv * wa.w;
    acc[4] += xv * wb.x; acc[5] += xv * wb.y; acc[6] += xv * wb.z; acc[7] += xv * wb.w;
  }
#pragma unroll
  for (int e = 0; e < 8; e++) {
    float v = acc[e];
#pragma unroll
    for (int m = 1; m < 64; m <<= 1) v += __shfl_xor(v, m, 64);
    acc[e] = v + br[e];
  }
  int i1 = 0; float m1 = acc[0];
#pragma unroll
  for (int e = 1; e < 8; e++) { if (acc[e] > m1) { m1 = acc[e]; i1 = e; } }
  int i2 = -1; float m2 = -3.4e38f;
#pragma unroll
  for (int e = 0; e < 8; e++) { if (e != i1 && acc[e] > m2) { m2 = acc[e]; i2 = e; } }
  if (l == 0) {
    e01[t] = i1 | (i2 << 8);
    p0arr[t] = 1.0f / (1.0f + __expf(m2 - m1));  // normalized top-1 prob
  }
}

// ---------------- slots: counts + exact offsets + slots + tile table --------
__global__ __launch_bounds__(1024) void slots_kernel(
    const int* __restrict__ e01, int* __restrict__ meta,
    int* __restrict__ slot1, int* __restrict__ slot2) {
  __shared__ int wtot[16];
  int tid = threadIdx.x;
  int l = tid & 63, wv = tid >> 6;
  int t0 = tid * 8;
  int i1[8], i2[8];
#pragma unroll
  for (int i = 0; i < 8; i++) {
    int ee = e01[t0 + i];
    i1[i] = ee & 255;
    i2[i] = (ee >> 8) & 255;
  }
  int offl[9];
  int running = 0;  // exact cumulative offset (identical in all threads)
  for (int e = 0; e < 8; e++) {
    offl[e] = running;
    int cthread = 0;
#pragma unroll
    for (int i = 0; i < 8; i++) cthread += (i1[i] == e) + (i2[i] == e);
    int inc = cthread;
#pragma unroll
    for (int d = 1; d < 64; d <<= 1) {
      int v = __shfl_up(inc, d, 64);
      if (l >= d) inc += v;
    }
    if (l == 63) wtot[wv] = inc;
    __syncthreads();
    int wbase = 0, total = 0;
#pragma unroll
    for (int w = 0; w < 16; w++) {
      int tw = wtot[w];
      wbase += (w < wv) ? tw : 0;
      total += tw;
    }
    int base = running + wbase + (inc - cthread);
#pragma unroll
    for (int i = 0; i < 8; i++) {
      if (i1[i] == e) { slot1[t0 + i] = base; base++; }
      if (i2[i] == e) { slot2[t0 + i] = base; base++; }
    }
    running += total;
    __syncthreads();  // protect wtot for next pass
  }
  offl[8] = running;
  if (tid == 0) {
#pragma unroll
    for (int e = 0; e < 9; e++) meta[e] = offl[e];
    int nt = 0;
    for (int e = 0; e < 8; e++)
      for (int r = offl[e]; r < offl[e + 1]; r += 256)
        meta[16 + (nt++)] = r | (e << 20);
    meta[10] = nt;
  }
}

// ---------------- gather: x -> bf16 into both expert slots ----------------
__global__ __launch_bounds__(256) void gather_kernel(
    const float* __restrict__ x, const int* __restrict__ slot1,
    const int* __restrict__ slot2, bf16* __restrict__ Xg) {
  int t = blockIdx.x;
  int s1 = slot1[t], s2 = slot2[t];
  float4 v = ((const float4*)(x + (size_t)t * 1024))[threadIdx.x];
  bf16x4 bv = { (bf16)v.x, (bf16)v.y, (bf16)v.z, (bf16)v.w };
  *(bf16x4*)(Xg + (size_t)s1 * 1024 + threadIdx.x * 4) = bv;
  *(bf16x4*)(Xg + (size_t)s2 * 1024 + threadIdx.x * 4) = bv;
}

// ---------- bijective chunked XCD tile map (m204 pattern) ----------
// total tiles = ntiles << nshift, flattened tidx = m_idx<<nshift | n (n fastest).
__device__ __forceinline__ bool xcd_tile(int b, int ntiles, int nshift,
                                         int& m_idx, int& n_tile) {
  int xcd = b & 7, j = b >> 3;
  int total = ntiles << nshift;
  int q = total >> 3, r = total & 7;
  int cnt = q + (xcd < r ? 1 : 0);
  if (j >= cnt) return false;
  int start = (xcd < r) ? xcd * (q + 1) : r * (q + 1) + (xcd - r) * q;
  int tidx = start + j;
  m_idx = tidx >> nshift;
  n_tile = tidx & ((1 << nshift) - 1);
  return true;
}

// ============ GEMM core (BM=256, BN=128, BK=32, 3-buffer ring) =============
// A [M][K] bf16 K-contig via GLD16 (A region 16KB @0 of 24KB buffer).
// B [K][Nw] fp32 native layout (Bw pre-offset to panel col 0): reg-staged.
//   Thread t: n=t&127, kh=t>>7; per K-step loads 16 fp32 down column n
//   (k = step*32 + kh*16 + i; each load wave-coalesced across n), cvt bf16,
//   2x ds_write_b128 at swizzled [n][k] (B region 8KB @16384).
// Per K-step: ph0 {read 4 B-frags + 4 A-frags, issue 16 B-loads then 4
// A-GLD16 (t+2), barrier, lgkm0, setprio, 16 MFMA, setprio, barrier};
// ph1 {read 4 A-frags, barrier, lgkm0, setprio, 16 MFMA, setprio,
// cvt+2 ds_write (compiler emits exact vmcnt(4) for fb; in-order retirement
// also lands A(t+1)), [vmcnt(0) drain if no stage], lgkm0, barrier}.
__device__ __forceinline__ void gemm_core(
    const bf16* __restrict__ Abase, const float* __restrict__ Bw, int Nw,
    int K, int NT, char* smem, f32x4 acc[8][4], int wr, int wc, int l) {
  int tid = threadIdx.x;
  size_t K2 = (size_t)K * 2;  // A row stride bytes
  const char* srcA[4];
  int dstA[4];
#pragma unroll
  for (int i = 0; i < 4; i++) {
    int byteoff = (tid + i * 256) * 16;  // [0,16384)
    int p = byteoff >> 7, W = byteoff & 127;
    int L = W ^ ((p & 7) << 4);
    int r = 2 * p + (L >> 6), c = L & 63;
    srcA[i] = (const char*)Abase + (size_t)r * K2 + c;
    dstA[i] = byteoff;
  }
  // B reg-staging constants
  int nloc = tid & 127, kh = tid >> 7;
  const float* bcur = Bw + (size_t)(kh * 16) * Nw + nloc;
  int pb = nloc >> 1;
  int wb0 = 16384 + (pb << 7) + ((((nloc & 1) << 6) | (kh * 32)) ^ ((pb & 7) << 4));
  int wb1 = wb0 ^ 16;  // kh*32 has bit4 clear -> +16 == ^16
  // fragment read offsets
  int offA[8], offB[4];
  int kc16 = (l >> 4) << 4;
#pragma unroll
  for (int mf = 0; mf < 8; mf++) {
    int r = wr * 128 + mf * 16 + (l & 15);
    int p = r >> 1;
    offA[mf] = (p << 7) + ((((r & 1) << 6) | kc16) ^ ((p & 7) << 4));
  }
#pragma unroll
  for (int nf = 0; nf < 4; nf++) {
    int r = wc * 64 + nf * 16 + (l & 15);
    int p = r >> 1;
    offB[nf] = 16384 + (p << 7) + ((((r & 1) << 6) | kc16) ^ ((p & 7) << 4));
  }
  float fb[16];
  // prologue: stage K-steps 0,1 (B loads first, then A GLD16 -> wait for fb
  // is vmcnt(4), leaving newest A in flight; in-order retirement covers rest)
#pragma unroll
  for (int t = 0; t < 2; t++) {
    char* bu = smem + t * 24576;
#pragma unroll
    for (int i = 0; i < 16; i++) fb[i] = bcur[(size_t)i * Nw];
    __builtin_amdgcn_sched_barrier(0);
#pragma unroll
    for (int i = 0; i < 4; i++) GLD16(srcA[i] + t * 64, bu + dstA[i]);
    __builtin_amdgcn_sched_barrier(0);
    bf16x8 h0, h1;
#pragma unroll
    for (int i = 0; i < 8; i++) { h0[i] = (bf16)fb[i]; h1[i] = (bf16)fb[i + 8]; }
    *(bf16x8*)(bu + wb0) = h0;
    *(bf16x8*)(bu + wb1) = h1;
    bcur += (size_t)32 * Nw;
  }
  asm volatile("s_waitcnt lgkmcnt(0)" ::: "memory");
  __builtin_amdgcn_s_barrier();
  char* bc = smem;                // compute buffer (step t)
  char* bs = smem + 2 * 24576;    // stage target (step t+2)
  for (int t = 0; t < NT; t++) {
    bool st = (t + 2) < NT;
    bf16x8 bfr[4], af[4];
    // ---- phase 0 ----
#pragma unroll
    for (int nf = 0; nf < 4; nf++) bfr[nf] = *(const bf16x8*)(bc + offB[nf]);
#pragma unroll
    for (int mf = 0; mf < 4; mf++) af[mf] = *(const bf16x8*)(bc + offA[mf]);
    if (st) {
#pragma unroll
      for (int i = 0; i < 16; i++) fb[i] = bcur[(size_t)i * Nw];
      __builtin_amdgcn_sched_barrier(0);
#pragma unroll
      for (int i = 0; i < 4; i++)
        GLD16(srcA[i] + (size_t)(t + 2) * 64, bs + dstA[i]);
      __builtin_amdgcn_sched_barrier(0);
    }
    __builtin_amdgcn_s_barrier();
    asm volatile("s_waitcnt lgkmcnt(0)" ::: "memory");
    __builtin_amdgcn_s_setprio(1);
#pragma unroll
    for (int mf = 0; mf < 4; mf++)
#pragma unroll
      for (int nf = 0; nf < 4; nf++)
        acc[mf][nf] = __builtin_amdgcn_mfma_f32_16x16x32_bf16(bfr[nf], af[mf], acc[mf][nf], 0, 0, 0);
    __builtin_amdgcn_s_setprio(0);
    __builtin_amdgcn_s_barrier();
    // ---- phase 1 ----
#pragma unroll
    for (int mf = 0; mf < 4; mf++) af[mf] = *(const bf16x8*)(bc + offA[mf + 4]);
    __builtin_amdgcn_s_barrier();
    asm volatile("s_waitcnt lgkmcnt(0)" ::: "memory");
    __builtin_amdgcn_s_setprio(1);
#pragma unroll
    for (int mf = 0; mf < 4; mf++)
#pragma unroll
      for (int nf = 0; nf < 4; nf++)
        acc[mf + 4][nf] = __builtin_amdgcn_mfma_f32_16x16x32_bf16(bfr[nf], af[mf], acc[mf + 4][nf], 0, 0, 0);
    __builtin_amdgcn_s_setprio(0);
    if (st) {
      // compiler inserts exact vmcnt wait for fb here (newest 4 = A-GLD16
      // stay outstanding); write B(t+2) into stage buffer
      bf16x8 h0, h1;
#pragma unroll
      for (int i = 0; i < 8; i++) { h0[i] = (bf16)fb[i]; h1[i] = (bf16)fb[i + 8]; }
      *(bf16x8*)(bs + wb0) = h0;
      *(bf16x8*)(bs + wb1) = h1;
      bcur += (size_t)32 * Nw;
    } else if (t + 1 < NT) {
      asm volatile("s_waitcnt vmcnt(0)" ::: "memory");  // drain last A loads
    }
    asm volatile("s_waitcnt lgkmcnt(0)" ::: "memory");
    __builtin_amdgcn_s_barrier();
    bc += 24576; if (bc == smem + 73728) bc = smem;
    bs += 24576; if (bs == smem + 73728) bs = smem;
  }
}

// ---------------- grouped GEMM1: h = gelu(Xg @ W1[e] + b1[e]) ----------------
// Grid 2304 = 8 xcd x 288; <=72 m-tiles (256 rows) x 32 n_tiles (128 cols).
// B = W1[e] : [K=1024][N=4096] fp32 native.
__global__ __launch_bounds__(256, 2) void gemm1_kernel(
    const bf16* __restrict__ Xg, const float* __restrict__ W1,
    const float* __restrict__ b1, bf16* __restrict__ hbuf,
    const int* __restrict__ meta) {
  __shared__ __align__(16) char smem[73728];
  int m_idx, n_tile;
  if (!xcd_tile(blockIdx.x, meta[10], 5, m_idx, n_tile)) return;
  int ti = meta[16 + m_idx];
  int row0 = ti & 0xFFFFF;
  int e = ti >> 20;
  int rowEnd = meta[1 + e];
  int tid = threadIdx.x;
  int w = tid >> 6, l = tid & 63;
  int wr = w >> 1, wc = w & 1;
  f32x4 acc[8][4];
#pragma unroll
  for (int a = 0; a < 8; a++)
#pragma unroll
    for (int bb = 0; bb < 4; bb++) acc[a][bb] = (f32x4){0.f, 0.f, 0.f, 0.f};
  gemm_core(Xg + (size_t)row0 * 1024,
            W1 + (size_t)e * 1024 * 4096 + n_tile * 128, 4096,
            1024, 32, smem, acc, wr, wc, l);
  int mrow = l & 15, nq = (l >> 4) * 4;
  int gn0 = n_tile * 128 + wc * 64 + nq;
  f32x4 bv[4];
#pragma unroll
  for (int nf = 0; nf < 4; nf++)
    bv[nf] = *(const f32x4*)(b1 + e * 4096 + gn0 + nf * 16);
#pragma unroll
  for (int mf = 0; mf < 8; mf++) {
    int gm = row0 + wr * 128 + mf * 16 + mrow;
    if (gm < rowEnd) {
      bf16* rp = hbuf + (size_t)gm * 4096 + gn0;
#pragma unroll
      for (int nf = 0; nf < 4; nf++) {
        bf16x4 o;
#pragma unroll
        for (int jj = 0; jj < 4; jj++)
          o[jj] = (bf16)gelu_fast(acc[mf][nf][jj] + bv[nf][jj]);
        *(bf16x4*)(rp + nf * 16) = o;
      }
    }
  }
}

// ---------------- grouped GEMM2: y[slot] = h @ W2[e] + b2[e] (bf16) ---------
// Grid 576 = 8 xcd x 72; <=72 m-tiles x 8 n_tiles.
// B = W2[e] : [K=4096][N=1024] fp32 native.
__global__ __launch_bounds__(256, 2) void gemm2_kernel(
    const bf16* __restrict__ hbuf, const float* __restrict__ W2,
    const float* __restrict__ b2, bf16* __restrict__ yb,
    const int* __restrict__ meta) {
  __shared__ __align__(16) char smem[73728];
  int m_idx, n_tile;
  if (!xcd_tile(blockIdx.x, meta[10], 3, m_idx, n_tile)) return;
  int ti = meta[16 + m_idx];
  int row0 = ti & 0xFFFFF;
  int e = ti >> 20;
  int rowEnd = meta[1 + e];
  int tid = threadIdx.x;
  int w = tid >> 6, l = tid & 63;
  int wr = w >> 1, wc = w & 1;
  f32x4 acc[8][4];
#pragma unroll
  for (int a = 0; a < 8; a++)
#pragma unroll
    for (int bb = 0; bb < 4; bb++) acc[a][bb] = (f32x4){0.f, 0.f, 0.f, 0.f};
  gemm_core(hbuf + (size_t)row0 * 4096,
            W2 + (size_t)e * 4096 * 1024 + n_tile * 128, 1024,
            4096, 128, smem, acc, wr, wc, l);
  int mrow = l & 15, nq = (l >> 4) * 4;
  int gn0 = n_tile * 128 + wc * 64 + nq;
  f32x4 bv[4];
#pragma unroll
  for (int nf = 0; nf < 4; nf++)
    bv[nf] = *(const f32x4*)(b2 + e * 1024 + gn0 + nf * 16);
#pragma unroll
  for (int mf = 0; mf < 8; mf++) {
    int gm = row0 + wr * 128 + mf * 16 + mrow;
    if (gm < rowEnd) {
      bf16* rp = yb + (size_t)gm * 1024 + gn0;
#pragma unroll
      for (int nf = 0; nf < 4; nf++) {
        bf16x4 o;
#pragma unroll
        for (int jj = 0; jj < 4; jj++)
          o[jj] = (bf16)(acc[mf][nf][jj] + bv[nf][jj]);
        *(bf16x4*)(rp + nf * 16) = o;
      }
    }
  }
}

// ---------------- combine: out[t] = p0[t] * (y[s1] + y[s2]) -----------------
__global__ __launch_bounds__(256) void combine_kernel(
    const bf16* __restrict__ yb, const int* __restrict__ slot1,
    const int* __restrict__ slot2, const float* __restrict__ p0arr,
    float* __restrict__ out) {
  int t = blockIdx.x;
  int s1 = slot1[t], s2 = slot2[t];
  float w0 = p0arr[t];
  bf16x4 a = *(const bf16x4*)(yb + (size_t)s1 * 1024 + threadIdx.x * 4);
  bf16x4 b = *(const bf16x4*)(yb + (size_t)s2 * 1024 + threadIdx.x * 4);
  float4 o;
  o.x = w0 * ((float)a[0] + (float)b[0]);
  o.y = w0 * ((float)a[1] + (float)b[1]);
  o.z = w0 * ((float)a[2] + (float)b[2]);
  o.w = w0 * ((float)a[3] + (float)b[3]);
  *(float4*)(out + (size_t)t * 1024 + threadIdx.x * 4) = o;
}

extern "C" void kernel_launch(void* const* d_in, const int* in_sizes, int n_in,
                              void* d_out, int out_size, void* d_ws, size_t ws_size,
                              hipStream_t stream) {
  const float* x  = (const float*)d_in[0];
  const float* Wr = (const float*)d_in[1];
  const float* br = (const float*)d_in[2];
  const float* W1 = (const float*)d_in[3];
  const float* b1 = (const float*)d_in[4];
  const float* W2 = (const float*)d_in[5];
  const float* b2 = (const float*)d_in[6];
  float* out = (float*)d_out;

  char* ws = (char*)d_ws;
  int*   meta  = (int*)(ws + 0);
  int*   e01   = (int*)(ws + 4096);
  float* p0    = (float*)(ws + 36864);
  int*   slot1 = (int*)(ws + 69632);
  int*   slot2 = (int*)(ws + 102400);
  bf16*  Xg    = (bf16*)(ws + 135168);          // reused as ybuf after gemm1
  bf16*  hb    = (bf16*)(ws + 168431616ULL);
  bf16*  yb    = Xg;

  router_kernel<<<2048, 256, 0, stream>>>(x, Wr, br, e01, p0);
  slots_kernel<<<1, 1024, 0, stream>>>(e01, meta, slot1, slot2);
  gather_kernel<<<8192, 256, 0, stream>>>(x, slot1, slot2, Xg);
  gemm1_kernel<<<2304, 256, 0, stream>>>(Xg, W1, b1, hb, meta);
  gemm2_kernel<<<576, 256, 0, stream>>>(hb, W2, b2, yb, meta);
  combine_kernel<<<8192, 256, 0, stream>>>(yb, slot1, slot2, p0, out);
}